// Round 6
// baseline (190.059 us; speedup 1.0000x reference)
//
#include <hip/hip_runtime.h>
#include <math.h>

#define BB 32
#define LL 256
#define DD 16
#define HH 64
#define KK 5
#define TT 252          // LL - KK + 1
#define PP 126          // TT/2
#define SS 8064         // HH*PP
#define NCHUNK 42
#define CHUNK 192       // SS / NCHUNK, multiple of 4
#define NCB 32          // col-blocks: 32 * 256 thr * 1 col = 8192 >= 8064

// ---------------- kernel 12: conv + relu + recon + pool (fused per (b,d)) --
__global__ __launch_bounds__(256) void k12_conv_recon(
    const float* __restrict__ x, const float* __restrict__ cw,
    const float* __restrict__ cb, const float* __restrict__ dw,
    const float* __restrict__ db, float* __restrict__ flat,
    float* __restrict__ mainTT, float* __restrict__ recon) {
  __shared__ float ylds[HH * TT];   // 64*252 = 16128 f = 64512 B
  __shared__ float xs[LL];          // 256 f
  __shared__ float cws[HH * KK];    // 320 f
  __shared__ float dws[HH * KK];    // 320 f
  __shared__ float cbs[HH];         // 64 f

  int bd = blockIdx.x;              // b*DD + d
  int b = bd / DD, d = bd % DD;
  int tid = threadIdx.x;

  // stage x column + weights (HH*KK = 320 > 256 -> strided loop)
  xs[tid] = x[((size_t)b * LL + tid) * DD + d];
  for (int i = tid; i < HH * KK; i += 256) {
    cws[i] = cw[(size_t)d * HH * KK + i];
    dws[i] = dw[(size_t)d * HH * KK + i];
  }
  if (tid < HH) cbs[tid] = cb[d * HH + tid];
  __syncthreads();

  // conv+relu: thread = (h, quarter a), sliding window over 63 t's
  {
    int h = tid >> 2, a = tid & 3;
    int t0 = a * 63;
    float w0 = cws[h * KK + 0], w1 = cws[h * KK + 1], w2 = cws[h * KK + 2],
          w3 = cws[h * KK + 3], w4 = cws[h * KK + 4];
    float bias = cbs[h];
    float x0 = xs[t0], x1 = xs[t0 + 1], x2 = xs[t0 + 2], x3 = xs[t0 + 3],
          x4 = xs[t0 + 4];
    float* yrow = ylds + h * TT + t0;
    #pragma unroll 7
    for (int t = 0; t < 63; ++t) {
      float yv = fmaf(w4, x4, fmaf(w3, x3, fmaf(w2, x2, fmaf(w1, x1, fmaf(w0, x0, bias)))));
      yrow[t] = fmaxf(yv, 0.f);
      x0 = x1; x1 = x2; x2 = x3; x3 = x4;
      if (t < 62) x4 = xs[t0 + t + 5];
    }
  }
  __syncthreads();

  // pair-pool -> flat (+ mainTT[b][s] for d==0)
  for (int i = tid; i < HH * PP; i += 256) {
    int h = i / PP, p = i - h * PP;
    float pooled = 0.5f * (ylds[h * TT + 2 * p] + ylds[h * TT + 2 * p + 1]);
    flat[(size_t)bd * SS + i] = pooled;
    if (d == 0) mainTT[(size_t)b * SS + i] = pooled;
  }

  // recon: thread = output position l
  {
    int l = tid;
    float acc = db[d];
    for (int h = 0; h < HH; ++h) {
      const float* yl = ylds + h * TT;
      #pragma unroll
      for (int j = 0; j < KK; ++j) {
        int t = l - j;
        if (t >= 0 && t < TT) acc = fmaf(yl[t], dws[h * KK + j], acc);
      }
    }
    recon[(size_t)bd * LL + l] = acc;
  }
}

// ---------------- kernel 3: partial = main @ W_attn (1 col/thread) ----------
// acc[32] scalar -> low VGPR -> grid 1344 blocks, ~21 waves/CU for latency hiding.
__global__ __launch_bounds__(256, 5) void k3_matmul(
    const float* __restrict__ W, const float* __restrict__ mainTT,
    float* __restrict__ partial) {
  int chunk = blockIdx.y;
  int s0 = chunk * CHUNK;
  int col = blockIdx.x * 256 + threadIdx.x;   // 0..8191
  bool ok = col < SS;
  int cc = ok ? col : SS - 1;

  float acc[BB];
  #pragma unroll
  for (int b = 0; b < BB; ++b) acc[b] = 0.f;

  const float* wbase = W + (size_t)s0 * SS + cc;
  const float* mb = mainTT + s0;    // block-uniform

  // prefetch W rows 0..3 (coalesced dword per lane)
  float w0 = wbase[0];
  float w1 = wbase[SS];
  float w2 = wbase[2 * (size_t)SS];
  float w3 = wbase[3 * (size_t)SS];

  for (int s = 0; s < CHUNK; s += 4) {
    float c0 = w0, c1 = w1, c2 = w2, c3 = w3;
    if (s + 4 < CHUNK) {
      const float* nr = wbase + (size_t)(s + 4) * SS;
      w0 = nr[0];
      w1 = nr[SS];
      w2 = nr[2 * (size_t)SS];
      w3 = nr[3 * (size_t)SS];
    }
    #pragma unroll
    for (int b = 0; b < BB; ++b) {
      float4 mv = *(const float4*)(mb + (size_t)b * SS + s);  // uniform, L1-broadcast
      acc[b] = fmaf(mv.x, c0, acc[b]);
      acc[b] = fmaf(mv.y, c1, acc[b]);
      acc[b] = fmaf(mv.z, c2, acc[b]);
      acc[b] = fmaf(mv.w, c3, acc[b]);
    }
  }

  if (ok) {
    #pragma unroll
    for (int b = 0; b < BB; ++b)
      partial[((size_t)chunk * BB + b) * SS + col] = acc[b];
  }
}

// ---------------- kernel 3b: reduce partials -> m (float4) ------------------
__global__ __launch_bounds__(64) void k3b_reduce(
    const float4* __restrict__ partial, float4* __restrict__ m) {
  int i = blockIdx.x * 64 + threadIdx.x;       // < BB*SS/4 = 64512
  float4 s = make_float4(0.f, 0.f, 0.f, 0.f);
  #pragma unroll
  for (int c = 0; c < NCHUNK; ++c) {
    float4 v = partial[(size_t)c * (BB * SS / 4) + i];
    s.x += v.x; s.y += v.y; s.z += v.z; s.w += v.w;
  }
  m[i] = s;
}

// ---------------- kernel 4: scores[b,d'] = <m[b,:], aux[b,d',:]> ------------
__global__ __launch_bounds__(256) void k4_scores(
    const float* __restrict__ m, const float* __restrict__ flat,
    float* __restrict__ scores) {
  int bd = blockIdx.x;            // b*15 + dd
  int b = bd / 15, dd = bd % 15;
  const float* mb = m + (size_t)b * SS;
  const float* ab = flat + ((size_t)b * DD + 1 + dd) * SS;
  float p = 0.f;
  for (int s = threadIdx.x; s < SS; s += 256) p = fmaf(mb[s], ab[s], p);
  #pragma unroll
  for (int o = 32; o; o >>= 1) p += __shfl_xor(p, o);
  __shared__ float red[4];
  if ((threadIdx.x & 63) == 0) red[threadIdx.x >> 6] = p;
  __syncthreads();
  if (threadIdx.x == 0) scores[bd] = red[0] + red[1] + red[2] + red[3];
}

// ---------------- kernel 5: softmax over 15 ---------------------------------
__global__ __launch_bounds__(64) void k5_softmax(
    const float* __restrict__ scores, float* __restrict__ attn_out) {
  int b = blockIdx.x;
  int lane = threadIdx.x;
  float v = (lane < 15) ? scores[b * 15 + lane] : -INFINITY;
  float mx = v;
  #pragma unroll
  for (int o = 32; o; o >>= 1) mx = fmaxf(mx, __shfl_xor(mx, o));
  float e = (lane < 15) ? expf(v - mx) : 0.f;
  float sum = e;
  #pragma unroll
  for (int o = 32; o; o >>= 1) sum += __shfl_xor(sum, o);
  if (lane < 15) attn_out[b * 15 + lane] = e / sum;
}

// ---------------- kernel 6: main copy + weighted sum ------------------------
__global__ __launch_bounds__(256) void k6_out(
    const float* __restrict__ flat, const float* __restrict__ attn,
    float* __restrict__ out) {
  int b = blockIdx.y;
  int s = blockIdx.x * 256 + threadIdx.x;
  if (s >= SS) return;
  const float* fb = flat + (size_t)b * DD * SS;
  out[(size_t)b * 2 * SS + s] = fb[s];
  float w = 0.f;
  #pragma unroll
  for (int d = 0; d < 15; ++d)
    w = fmaf(attn[b * 15 + d], fb[(size_t)(1 + d) * SS + s], w);
  out[(size_t)b * 2 * SS + SS + s] = w;
}

// ---------------------------------------------------------------------------
extern "C" void kernel_launch(void* const* d_in, const int* in_sizes, int n_in,
                              void* d_out, int out_size, void* d_ws, size_t ws_size,
                              hipStream_t stream) {
  const float* x        = (const float*)d_in[0];
  const float* conv_w   = (const float*)d_in[1];
  const float* conv_b   = (const float*)d_in[2];
  const float* deconv_w = (const float*)d_in[3];
  const float* deconv_b = (const float*)d_in[4];
  const float* W_attn   = (const float*)d_in[5];
  float* out = (float*)d_out;

  // output layout: [ out (516096) | attn (480) | recon (131072) ]
  const size_t ATTN_OFF  = (size_t)BB * 2 * SS;        // 516096
  const size_t RECON_OFF = ATTN_OFF + (size_t)BB * 15; // 516576

  // workspace layout (floats); all offsets multiple of 4 -> 16B aligned
  float* ws      = (float*)d_ws;
  float* partial = ws;                                    // 42*32*8064 = 10,838,016
  float* flat    = partial + (size_t)NCHUNK * BB * SS;    // 4,128,768
  float* mainTT  = flat + (size_t)BB * DD * SS;           // 258,048  [b][s]
  float* m       = mainTT + (size_t)BB * SS;              // 258,048
  float* scores  = m + (size_t)BB * SS;                   // 480

  // 1) fused conv+relu+recon+pool
  k12_conv_recon<<<dim3(BB * DD), dim3(256), 0, stream>>>(
      x, conv_w, conv_b, deconv_w, deconv_b, flat, mainTT, out + RECON_OFF);

  // 2) big matmul partials
  k3_matmul<<<dim3(NCB, NCHUNK), dim3(256), 0, stream>>>(W_attn, mainTT, partial);

  // 3) reduce -> m
  k3b_reduce<<<dim3((BB * SS / 4) / 64), dim3(64), 0, stream>>>(
      (const float4*)partial, (float4*)m);

  // 4) scores
  k4_scores<<<dim3(BB * 15), dim3(256), 0, stream>>>(m, flat, scores);

  // 5) softmax -> attn section of out
  k5_softmax<<<dim3(BB), dim3(64), 0, stream>>>(scores, out + ATTN_OFF);

  // 6) main copy + weighted
  k6_out<<<dim3((SS + 255) / 256, BB), dim3(256), 0, stream>>>(
      flat, out + ATTN_OFF, out);
}

// Round 7
// 132.081 us; speedup vs baseline: 1.4390x; 1.4390x over previous
//
#include <hip/hip_runtime.h>
#include <math.h>

#define BB 32
#define LL 256
#define DD 16
#define HH 64
#define KK 5
#define TT 252          // LL - KK + 1
#define PP 126          // TT/2
#define SS 8064         // HH*PP
#define NCHUNK 42
#define CHUNK 192       // SS / NCHUNK, multiple of 4
#define NCB 32          // col-blocks: 32 * 256 thr * 1 col = 8192 >= 8064

// ---------------- kernel 12: conv + relu + recon + pool (fused per (b,d)) --
__global__ __launch_bounds__(256) void k12_conv_recon(
    const float* __restrict__ x, const float* __restrict__ cw,
    const float* __restrict__ cb, const float* __restrict__ dw,
    const float* __restrict__ db, float* __restrict__ flat,
    float* __restrict__ mainT, float* __restrict__ recon) {
  __shared__ float ylds[HH * TT];   // 64*252 = 16128 f = 64512 B
  __shared__ float xs[LL];          // 256 f
  __shared__ float cws[HH * KK];    // 320 f
  __shared__ float dws[HH * KK];    // 320 f
  __shared__ float cbs[HH];         // 64 f

  int bd = blockIdx.x;              // b*DD + d
  int b = bd / DD, d = bd % DD;
  int tid = threadIdx.x;

  // stage x column + weights (HH*KK = 320 > 256 -> strided loop)
  xs[tid] = x[((size_t)b * LL + tid) * DD + d];
  for (int i = tid; i < HH * KK; i += 256) {
    cws[i] = cw[(size_t)d * HH * KK + i];
    dws[i] = dw[(size_t)d * HH * KK + i];
  }
  if (tid < HH) cbs[tid] = cb[d * HH + tid];
  __syncthreads();

  // conv+relu: thread = (h, quarter a), sliding window over 63 t's
  {
    int h = tid >> 2, a = tid & 3;
    int t0 = a * 63;
    float w0 = cws[h * KK + 0], w1 = cws[h * KK + 1], w2 = cws[h * KK + 2],
          w3 = cws[h * KK + 3], w4 = cws[h * KK + 4];
    float bias = cbs[h];
    float x0 = xs[t0], x1 = xs[t0 + 1], x2 = xs[t0 + 2], x3 = xs[t0 + 3],
          x4 = xs[t0 + 4];
    float* yrow = ylds + h * TT + t0;
    #pragma unroll 7
    for (int t = 0; t < 63; ++t) {
      float yv = fmaf(w4, x4, fmaf(w3, x3, fmaf(w2, x2, fmaf(w1, x1, fmaf(w0, x0, bias)))));
      yrow[t] = fmaxf(yv, 0.f);
      x0 = x1; x1 = x2; x2 = x3; x3 = x4;
      if (t < 62) x4 = xs[t0 + t + 5];
    }
  }
  __syncthreads();

  // pair-pool -> flat (+ mainT[s][b] for d==0)
  for (int i = tid; i < HH * PP; i += 256) {
    int h = i / PP, p = i - h * PP;
    float pooled = 0.5f * (ylds[h * TT + 2 * p] + ylds[h * TT + 2 * p + 1]);
    flat[(size_t)bd * SS + i] = pooled;
    if (d == 0) mainT[(size_t)i * BB + b] = pooled;
  }

  // recon: thread = output position l
  {
    int l = tid;
    float acc = db[d];
    for (int h = 0; h < HH; ++h) {
      const float* yl = ylds + h * TT;
      #pragma unroll
      for (int j = 0; j < KK; ++j) {
        int t = l - j;
        if (t >= 0 && t < TT) acc = fmaf(yl[t], dws[h * KK + j], acc);
      }
    }
    recon[(size_t)bd * LL + l] = acc;
  }
}

// ---------------- kernel 3: partial = main @ W_attn (1 col/thread) ----------
// Accumulators in NAMED float4 registers a0..a7 (32 batches) — never an
// indexed array, so they cannot be demoted to scratch (round-6 bug: VGPR=28
// with acc[32] => spilled). m read as uniform float4s from mainT[s][b].
#define FMA4(A, Q, C)                                        \
  A.x = fmaf(Q.x, C, A.x); A.y = fmaf(Q.y, C, A.y);          \
  A.z = fmaf(Q.z, C, A.z); A.w = fmaf(Q.w, C, A.w);

#define MSTEP(C, SOFF) {                                     \
  const float4* mr = (const float4*)(mb + (size_t)(s + SOFF) * BB); \
  float4 q0 = mr[0], q1 = mr[1], q2 = mr[2], q3 = mr[3],     \
         q4 = mr[4], q5 = mr[5], q6 = mr[6], q7 = mr[7];     \
  FMA4(a0, q0, C) FMA4(a1, q1, C) FMA4(a2, q2, C)            \
  FMA4(a3, q3, C) FMA4(a4, q4, C) FMA4(a5, q5, C)            \
  FMA4(a6, q6, C) FMA4(a7, q7, C) }

#define ST4(A, B0)                                           \
  pp[(size_t)(B0) * SS] = A.x;  pp[(size_t)(B0 + 1) * SS] = A.y; \
  pp[(size_t)(B0 + 2) * SS] = A.z; pp[(size_t)(B0 + 3) * SS] = A.w;

__global__ __launch_bounds__(256) void k3_matmul(
    const float* __restrict__ W, const float* __restrict__ mainT,
    float* __restrict__ partial) {
  int chunk = blockIdx.y;
  int s0 = chunk * CHUNK;
  int col = blockIdx.x * 256 + threadIdx.x;   // 0..8191
  bool ok = col < SS;
  int cc = ok ? col : SS - 1;

  float4 z = make_float4(0.f, 0.f, 0.f, 0.f);
  float4 a0 = z, a1 = z, a2 = z, a3 = z, a4 = z, a5 = z, a6 = z, a7 = z;

  const float* wp = W + (size_t)s0 * SS + cc;
  const float* mb = mainT + (size_t)s0 * BB;

  // prefetch W rows 0..3 (coalesced dword per lane)
  float w0 = wp[0];
  float w1 = wp[(size_t)SS];
  float w2 = wp[2 * (size_t)SS];
  float w3 = wp[3 * (size_t)SS];

  for (int s = 0; s < CHUNK; s += 4) {
    float c0 = w0, c1 = w1, c2 = w2, c3 = w3;
    if (s + 4 < CHUNK) {
      const float* nr = wp + (size_t)(s + 4) * SS;
      w0 = nr[0];
      w1 = nr[(size_t)SS];
      w2 = nr[2 * (size_t)SS];
      w3 = nr[3 * (size_t)SS];
    }
    MSTEP(c0, 0)
    MSTEP(c1, 1)
    MSTEP(c2, 2)
    MSTEP(c3, 3)
  }

  if (ok) {
    float* pp = partial + (size_t)chunk * BB * SS + col;
    ST4(a0, 0)  ST4(a1, 4)  ST4(a2, 8)  ST4(a3, 12)
    ST4(a4, 16) ST4(a5, 20) ST4(a6, 24) ST4(a7, 28)
  }
}

// ---------------- kernel 3b: reduce partials -> m (float4) ------------------
__global__ __launch_bounds__(64) void k3b_reduce(
    const float4* __restrict__ partial, float4* __restrict__ m) {
  int i = blockIdx.x * 64 + threadIdx.x;       // < BB*SS/4 = 64512
  float4 s = make_float4(0.f, 0.f, 0.f, 0.f);
  #pragma unroll
  for (int c = 0; c < NCHUNK; ++c) {
    float4 v = partial[(size_t)c * (BB * SS / 4) + i];
    s.x += v.x; s.y += v.y; s.z += v.z; s.w += v.w;
  }
  m[i] = s;
}

// ---------------- kernel 4: scores[b,d'] = <m[b,:], aux[b,d',:]> ------------
__global__ __launch_bounds__(256) void k4_scores(
    const float* __restrict__ m, const float* __restrict__ flat,
    float* __restrict__ scores) {
  int bd = blockIdx.x;            // b*15 + dd
  int b = bd / 15, dd = bd % 15;
  const float* mb = m + (size_t)b * SS;
  const float* ab = flat + ((size_t)b * DD + 1 + dd) * SS;
  float p = 0.f;
  for (int s = threadIdx.x; s < SS; s += 256) p = fmaf(mb[s], ab[s], p);
  #pragma unroll
  for (int o = 32; o; o >>= 1) p += __shfl_xor(p, o);
  __shared__ float red[4];
  if ((threadIdx.x & 63) == 0) red[threadIdx.x >> 6] = p;
  __syncthreads();
  if (threadIdx.x == 0) scores[bd] = red[0] + red[1] + red[2] + red[3];
}

// ---------------- kernel 5: softmax over 15 ---------------------------------
__global__ __launch_bounds__(64) void k5_softmax(
    const float* __restrict__ scores, float* __restrict__ attn_out) {
  int b = blockIdx.x;
  int lane = threadIdx.x;
  float v = (lane < 15) ? scores[b * 15 + lane] : -INFINITY;
  float mx = v;
  #pragma unroll
  for (int o = 32; o; o >>= 1) mx = fmaxf(mx, __shfl_xor(mx, o));
  float e = (lane < 15) ? expf(v - mx) : 0.f;
  float sum = e;
  #pragma unroll
  for (int o = 32; o; o >>= 1) sum += __shfl_xor(sum, o);
  if (lane < 15) attn_out[b * 15 + lane] = e / sum;
}

// ---------------- kernel 6: main copy + weighted sum ------------------------
__global__ __launch_bounds__(256) void k6_out(
    const float* __restrict__ flat, const float* __restrict__ attn,
    float* __restrict__ out) {
  int b = blockIdx.y;
  int s = blockIdx.x * 256 + threadIdx.x;
  if (s >= SS) return;
  const float* fb = flat + (size_t)b * DD * SS;
  out[(size_t)b * 2 * SS + s] = fb[s];
  float w = 0.f;
  #pragma unroll
  for (int d = 0; d < 15; ++d)
    w = fmaf(attn[b * 15 + d], fb[(size_t)(1 + d) * SS + s], w);
  out[(size_t)b * 2 * SS + SS + s] = w;
}

// ---------------------------------------------------------------------------
extern "C" void kernel_launch(void* const* d_in, const int* in_sizes, int n_in,
                              void* d_out, int out_size, void* d_ws, size_t ws_size,
                              hipStream_t stream) {
  const float* x        = (const float*)d_in[0];
  const float* conv_w   = (const float*)d_in[1];
  const float* conv_b   = (const float*)d_in[2];
  const float* deconv_w = (const float*)d_in[3];
  const float* deconv_b = (const float*)d_in[4];
  const float* W_attn   = (const float*)d_in[5];
  float* out = (float*)d_out;

  // output layout: [ out (516096) | attn (480) | recon (131072) ]
  const size_t ATTN_OFF  = (size_t)BB * 2 * SS;        // 516096
  const size_t RECON_OFF = ATTN_OFF + (size_t)BB * 15; // 516576

  // workspace layout (floats); all offsets multiple of 4 -> 16B aligned
  float* ws      = (float*)d_ws;
  float* partial = ws;                                    // 42*32*8064 = 10,838,016
  float* flat    = partial + (size_t)NCHUNK * BB * SS;    // 4,128,768
  float* mainT   = flat + (size_t)BB * DD * SS;           // 258,048  [s][b]
  float* m       = mainT + (size_t)BB * SS;               // 258,048  [b][s]
  float* scores  = m + (size_t)BB * SS;                   // 480

  // 1) fused conv+relu+recon+pool
  k12_conv_recon<<<dim3(BB * DD), dim3(256), 0, stream>>>(
      x, conv_w, conv_b, deconv_w, deconv_b, flat, mainT, out + RECON_OFF);

  // 2) big matmul partials
  k3_matmul<<<dim3(NCB, NCHUNK), dim3(256), 0, stream>>>(W_attn, mainT, partial);

  // 3) reduce -> m
  k3b_reduce<<<dim3((BB * SS / 4) / 64), dim3(64), 0, stream>>>(
      (const float4*)partial, (float4*)m);

  // 4) scores
  k4_scores<<<dim3(BB * 15), dim3(256), 0, stream>>>(m, flat, scores);

  // 5) softmax -> attn section of out
  k5_softmax<<<dim3(BB), dim3(64), 0, stream>>>(scores, out + ATTN_OFF);

  // 6) main copy + weighted
  k6_out<<<dim3((SS + 255) / 256, BB), dim3(256), 0, stream>>>(
      flat, out + ATTN_OFF, out);
}